// Round 6
// baseline (197.276 us; speedup 1.0000x reference)
//
#include <hip/hip_runtime.h>

#define BATCH 32
#define NDIM 512
#define LNUM 8
#define KDIM 8

// per-batch workspace layout (float offsets)
#define WS_PM     0        // int[512]  posmap: node -> pos in S, or -1
#define WS_S      512      // int[64]   S (padded with 0 beyond s)
#define WS_ACT    640      // float[512] active mask (0 if in wavelet set)
#define WS_W      1152     // float[64*64]
#define WS_B2     5248     // float[64*64] B2 = W A_SS W^T
#define WS_C2     9344     // float[64*64] C2 = W^T D_SS W
#define WS_RA     13440    // float[64*512]
#define WS_RD     46208    // float[64*512]
#define WS_STRIDE 78976

#define LSTR 65            // LDS row stride for 64-wide tiles (conflict-free cols)
#define ASTR 33            // LDS stride for 32-col tiles

typedef float f4 __attribute__((ext_vector_type(4)));   // clang vector: OK for nontemporal builtins

// ---------------------------------------------------------------------------
// k_prep: grid (BATCH, 17).
//   parts 0..15 : RA/RD for a 32-column chunk (W rebuilt locally -> no dep)
//   part  16    : serial chain (posmap/act/W/B2/C2 to global for k_big)
// The two paths are independent, so they overlap inside one dispatch.
__global__ __launch_bounds__(256) void k_prep(
    const float* __restrict__ A, const float* __restrict__ O,
    const int* __restrict__ indices, const int* __restrict__ wavelet,
    float* __restrict__ ws)
{
    const int b = blockIdx.x;
    const int part = blockIdx.y;        // 0..16
    const int tid = threadIdx.x;
    float* base = ws + (size_t)b * WS_STRIDE;

    __shared__ float Wl[64*LSTR];
    __shared__ float pool[3*64*LSTR];   // chain: P1|P2|B2l ; rard: AS|RAt
    __shared__ int   pml[NDIM];
    __shared__ float actl[NDIM];
    __shared__ float actS[64];
    __shared__ int   idxsh[64];
    __shared__ int   Ssh[64];
    __shared__ int   prow[KDIM];
    __shared__ float Oall[LNUM*KDIM*KDIM];
    __shared__ int   s_sh;

    // ---- common setup ----
    for (int t = tid; t < LNUM*KDIM*KDIM; t += 256) {
        int l = t >> 6, k = t & 63;
        Oall[t] = O[((size_t)l*BATCH + b)*(KDIM*KDIM) + k];
    }
    if (tid < 64) idxsh[tid] = indices[b*64 + tid];
    for (int n = tid; n < NDIM; n += 256) { pml[n] = -1; actl[n] = 1.f; }
    __syncthreads();

    if (tid < 64) {
        int n = idxsh[tid];
        bool first = true;
        for (int t = 0; t < tid; ++t) if (idxsh[t] == n) first = false;
        unsigned long long m = __ballot(first);
        int rank = __popcll(m & ((1ull << tid) - 1ull));
        if (first) { pml[n] = rank; Ssh[rank] = n; }
        if (tid == 0) s_sh = (int)__popcll(m);
    }
    if (tid >= 64 && tid < 64 + LNUM) {
        actl[wavelet[b*LNUM + (tid - 64)]] = 0.f;
    }
    __syncthreads();
    const int s = s_sh;
    if (tid < 64 && tid >= s) Ssh[tid] = 0;
    __syncthreads();
    if (tid < 64) actS[tid] = actl[Ssh[tid]];

    // ---- common W build (tmp staged in pool) ----
    for (int t = tid; t < 4096; t += 256) {
        int rr = t >> 6, cc = t & 63;
        Wl[rr*LSTR + cc] = (rr == cc && rr < s) ? 1.f : 0.f;
    }
    __syncthreads();
    for (int l = 0; l < LNUM; ++l) {
        if (tid < KDIM) prow[tid] = pml[idxsh[l*KDIM + tid]];
        __syncthreads();
        for (int t = tid; t < KDIM*64; t += 256) {
            int i = t >> 6, c = t & 63;
            float acc = 0.f;
            #pragma unroll
            for (int j = 0; j < KDIM; ++j)
                acc += Oall[l*64 + i*KDIM + j] * Wl[prow[j]*LSTR + c];
            pool[t] = acc;
        }
        __syncthreads();
        for (int t = tid; t < KDIM*64; t += 256) {
            int i = t >> 6, c = t & 63;
            Wl[prow[i]*LSTR + c] = pool[t];
        }
        __syncthreads();
    }

    if (part == 16) {
        // =============== chain path ===============
        float* P1  = pool;
        float* P2  = pool + 64*LSTR;
        float* B2l = pool + 2*64*LSTR;

        {
            int*   g_posmap = (int*)(base + WS_PM);
            int*   g_S      = (int*)(base + WS_S);
            float* g_act    = base + WS_ACT;
            float* g_W      = base + WS_W;
            for (int n = tid; n < NDIM; n += 256) { g_posmap[n] = pml[n]; g_act[n] = actl[n]; }
            if (tid < 64) g_S[tid] = Ssh[tid];
            for (int t = tid; t < 4096; t += 256) g_W[t] = Wl[(t>>6)*LSTR + (t&63)];
        }

        // gather A_SS -> P1
        for (int t = tid; t < 4096; t += 256) {
            int n = t >> 6, m = t & 63;
            P1[n*LSTR + m] = A[((size_t)b*NDIM + Ssh[n])*NDIM + Ssh[m]];
        }
        __syncthreads();

        const int w = tid >> 6;
        const int ln = tid & 63;
        float acc[16];

        // T = W * A_SS -> P2
        #pragma unroll
        for (int k = 0; k < 16; ++k) acc[k] = 0.f;
        for (int n = 0; n < 64; ++n) {
            float as = P1[n*LSTR + ln];
            #pragma unroll
            for (int k = 0; k < 16; ++k) acc[k] += Wl[(w*16 + k)*LSTR + n] * as;
        }
        #pragma unroll
        for (int k = 0; k < 16; ++k) P2[(w*16 + k)*LSTR + ln] = acc[k];
        __syncthreads();

        // B2 = T * W^T -> B2l + global
        #pragma unroll
        for (int k = 0; k < 16; ++k) acc[k] = 0.f;
        for (int m = 0; m < 64; ++m) {
            float wv = Wl[ln*LSTR + m];
            #pragma unroll
            for (int k = 0; k < 16; ++k) acc[k] += P2[(w*16 + k)*LSTR + m] * wv;
        }
        #pragma unroll
        for (int k = 0; k < 16; ++k) B2l[(w*16 + k)*LSTR + ln] = acc[k];
        __syncthreads();
        {
            float* g_B2 = base + WS_B2;
            for (int t = tid; t < 4096; t += 256) g_B2[t] = B2l[(t>>6)*LSTR + (t&63)];
        }

        // D_SS = mask .* B2 -> P1
        for (int t = tid; t < 4096; t += 256) {
            int n = t >> 6, m = t & 63;
            float mv = (Ssh[n] == Ssh[m]) ? 1.f : actS[n]*actS[m];
            P1[n*LSTR + m] = mv * B2l[n*LSTR + m];
        }
        __syncthreads();

        // T2 = W^T * D_SS -> P2
        #pragma unroll
        for (int k = 0; k < 16; ++k) acc[k] = 0.f;
        for (int n = 0; n < 64; ++n) {
            float dv = P1[n*LSTR + ln];
            #pragma unroll
            for (int k = 0; k < 16; ++k) acc[k] += Wl[n*LSTR + (w*16 + k)] * dv;
        }
        #pragma unroll
        for (int k = 0; k < 16; ++k) P2[(w*16 + k)*LSTR + ln] = acc[k];
        __syncthreads();

        // C2 = T2 * W -> global
        #pragma unroll
        for (int k = 0; k < 16; ++k) acc[k] = 0.f;
        for (int m = 0; m < 64; ++m) {
            float wv = Wl[m*LSTR + ln];
            #pragma unroll
            for (int k = 0; k < 16; ++k) acc[k] += P2[(w*16 + k)*LSTR + m] * wv;
        }
        {
            float* g_C2 = base + WS_C2;
            #pragma unroll
            for (int k = 0; k < 16; ++k) g_C2[(w*16 + k)*64 + ln] = acc[k];
        }
    } else {
        // =============== rard path (32 columns) ===============
        float* AS  = pool;
        float* RAt = pool + 64*ASTR;
        float* g_RA = base + WS_RA;
        float* g_RD = base + WS_RD;
        const int j0 = part * 32;

        // gather A_S tile: AS[n][c] = A[b][S[n]][j0+c]
        for (int t = tid; t < 2048; t += 256) {
            int n = t >> 5, c = t & 31;
            AS[n*ASTR + c] = A[((size_t)b*NDIM + Ssh[n])*NDIM + j0 + c];
        }
        __syncthreads();

        const int c = tid & 31;
        const int g = tid >> 5;        // rows g*8..g*8+7
        float acc[8];

        // RA[m][j] = sum_n W[m][n] * AS[n][c]
        #pragma unroll
        for (int k = 0; k < 8; ++k) acc[k] = 0.f;
        for (int n = 0; n < 64; ++n) {
            float av = AS[n*ASTR + c];
            #pragma unroll
            for (int k = 0; k < 8; ++k) acc[k] += Wl[(g*8 + k)*LSTR + n] * av;
        }
        #pragma unroll
        for (int k = 0; k < 8; ++k) {
            RAt[(g*8 + k)*ASTR + c] = acc[k];
            g_RA[(g*8 + k)*NDIM + j0 + c] = acc[k];
        }
        __syncthreads();

        // RD[q][j] = sum_n W[n][q] * actS[n]*actj * RAt[n][c]
        // (S-columns of RA/RD are never consumed by k_big -> no pj branch)
        const float actj = actl[j0 + c];
        #pragma unroll
        for (int k = 0; k < 8; ++k) acc[k] = 0.f;
        for (int n = 0; n < 64; ++n) {
            float dv = actS[n] * actj * RAt[n*ASTR + c];
            #pragma unroll
            for (int k = 0; k < 8; ++k) acc[k] += Wl[n*LSTR + g*8 + k] * dv;
        }
        #pragma unroll
        for (int k = 0; k < 8; ++k)
            g_RD[(g*8 + k)*NDIM + j0 + c] = acc[k];
    }
}

// ---------------------------------------------------------------------------
// one float4-vectorized pass over (b,i,j): write A_rec, right, D
// Outputs are streaming -> nontemporal stores keep A/RA/RD cache-resident.
__global__ __launch_bounds__(256) void k_big(const float* __restrict__ A,
                                             const float* __restrict__ ws,
                                             float* __restrict__ out)
{
    const int b = blockIdx.y;
    const int rh = threadIdx.x >> 7;          // 2 rows per block
    const int lane = threadIdx.x & 127;       // 128 float4s per row
    const int i = blockIdx.x*2 + rh;
    const int j0 = lane*4;

    const float* base = ws + (size_t)b * WS_STRIDE;
    const int*   posmap = (const int*)(base + WS_PM);
    const float* act = base + WS_ACT;
    const float* g_W  = base + WS_W;
    const float* g_B2 = base + WS_B2;
    const float* g_C2 = base + WS_C2;
    const float* RA = base + WS_RA;
    const float* RD = base + WS_RD;

    const int pi = posmap[i];
    const float acti = act[i];
    const size_t rowoff = ((size_t)b*NDIM + i)*NDIM;
    const size_t seg = (size_t)BATCH*NDIM*NDIM;

    int4   p4  = ((const int4*)posmap)[lane];
    float4 aj4 = ((const float4*)act)[lane];
    int   pm[4] = {p4.x, p4.y, p4.z, p4.w};
    float aj[4] = {aj4.x, aj4.y, aj4.z, aj4.w};

    float a[4], arec[4], dv[4], rv[4];

    if (pi < 0) {
        float4 v = ((const float4*)(A + rowoff))[lane];
        a[0]=v.x; a[1]=v.y; a[2]=v.z; a[3]=v.w;
        #pragma unroll
        for (int c = 0; c < 4; ++c) {
            int pj = pm[c];
            if (pj >= 0) a[c] = RA[pj*NDIM + i];
            float mv = (i == j0 + c) ? 1.f : acti * aj[c];
            dv[c] = a[c] * mv;
            arec[c] = (pj < 0) ? dv[c] : RD[pj*NDIM + i];
            rv[c] = (i == j0 + c) ? 1.f : 0.f;
        }
    } else {
        float4 v = ((const float4*)(RA + pi*NDIM))[lane];
        float4 w = ((const float4*)(RD + pi*NDIM))[lane];
        a[0]=v.x; a[1]=v.y; a[2]=v.z; a[3]=v.w;
        arec[0]=w.x; arec[1]=w.y; arec[2]=w.z; arec[3]=w.w;
        #pragma unroll
        for (int c = 0; c < 4; ++c) {
            int pj = pm[c];
            if (pj >= 0) {
                a[c]    = g_B2[pi*64 + pj];
                arec[c] = g_C2[pi*64 + pj];
                rv[c]   = g_W[pi*64 + pj];
            } else {
                rv[c] = 0.f;
            }
            float mv = (i == j0 + c) ? 1.f : acti * aj[c];
            dv[c] = a[c] * mv;
        }
    }

    f4 v0 = { arec[0], arec[1], arec[2], arec[3] };
    f4 v1 = { rv[0],   rv[1],   rv[2],   rv[3]   };
    f4 v2 = { dv[0],   dv[1],   dv[2],   dv[3]   };
    __builtin_nontemporal_store(v0, (f4*)(out + rowoff) + lane);
    __builtin_nontemporal_store(v1, (f4*)(out + seg + rowoff) + lane);
    __builtin_nontemporal_store(v2, (f4*)(out + 2*seg + rowoff) + lane);
}

extern "C" void kernel_launch(void* const* d_in, const int* in_sizes, int n_in,
                              void* d_out, int out_size, void* d_ws, size_t ws_size,
                              hipStream_t stream) {
    const float* A       = (const float*)d_in[0];
    const float* O       = (const float*)d_in[1];
    const int*   indices = (const int*)d_in[2];
    const int*   wavelet = (const int*)d_in[3];
    float* ws  = (float*)d_ws;   // needs ~10.1 MB
    float* out = (float*)d_out;

    k_prep<<<dim3(BATCH, 17), 256, 0, stream>>>(A, O, indices, wavelet, ws);
    k_big <<<dim3(NDIM/2, BATCH), 256, 0, stream>>>(A, ws, out);
}